// Round 1
// baseline (13243.867 us; speedup 1.0000x reference)
//
#include <hip/hip_runtime.h>
#include <hip/hip_bf16.h>

typedef unsigned short u16;
typedef u16 u16x8 __attribute__((ext_vector_type(8)));

// ---------------------------------------------------------------------------
// Problem constants: B=32, N=64, DI=DO=R=256.
// Output: out_nodes [32,64,256] f32 (524288) then adj [32,64,64] f32 (131072).
//
// Workspace layout (floats):
//   rep  @ 0        (2048*256)
//   pf   @ 524288   rep@Wf3 + b_forget
//   ph   @ 1048576  rep@Wh3 + b_hid
//   pq   @ 1572864  rep@Wq2 + b_query
//   po   @ 2097152  rep@Wo2 + b_out
//   panels (u16) @ float offset 2621440: 12 panels of 65536 bf16 each,
//   blocked layout [cb=16][k=256][cc=16] so wave w streams slice cb=w.
// ---------------------------------------------------------------------------

// ---------------- precompute GEMM: C = A[M,256] @ B[256,256] + bias --------
struct G4 { const float* Bm[4]; const float* bias[4]; float* C[4]; };

__global__ __launch_bounds__(256) void gemm16(const float* __restrict__ A, G4 g) {
  __shared__ float At[16 * 256];
  const int sub = blockIdx.y;
  const float* __restrict__ Bm = g.Bm[sub];
  const float* __restrict__ bias = g.bias[sub];
  float* __restrict__ C = g.C[sub];
  const int r0 = blockIdx.x * 16;
  const int t = threadIdx.x;
#pragma unroll
  for (int j = 0; j < 16; ++j) At[j * 256 + t] = A[(r0 + j) * 256 + t];
  __syncthreads();
  float acc[16];
#pragma unroll
  for (int j = 0; j < 16; ++j) acc[j] = 0.f;
  for (int k = 0; k < 256; ++k) {
    const float bv = Bm[k * 256 + t];
#pragma unroll
    for (int j = 0; j < 16; ++j) acc[j] = fmaf(At[j * 256 + k], bv, acc[j]);
  }
  const float bs = bias[t];
#pragma unroll
  for (int j = 0; j < 16; ++j) C[(r0 + j) * 256 + t] = acc[j] + bs;
}

// ---------------- weight conversion to blocked bf16 panels -----------------
struct C12 { const float* src[12]; };

__global__ __launch_bounds__(256) void cvt_panels(C12 c, u16* __restrict__ dst) {
  const int z = blockIdx.y;
  const float* __restrict__ in = c.src[z];
  u16* __restrict__ out = dst + z * 65536;
  const int e = blockIdx.x * 256 + threadIdx.x;   // panel-linear out index
  const int cb = e >> 12, k = (e >> 4) & 255, cc = e & 15;
  union { __hip_bfloat16 h; u16 u; } cv;
  cv.h = __float2bfloat16(in[k * 256 + cb * 16 + cc]);
  out[e] = cv.u;
}

// ---------------- main sequential recurrence kernel ------------------------
// Panel element offsets (u16 units)
#define PF_WF1 0
#define PF_WF2 65536
#define PF_WF4 131072
#define PF_WH1 196608
#define PF_WH2 262144
#define PF_WH4 327680
#define PF_WQ1 393216
#define PF_WQ3 458752
#define PF_WO1 524288
#define PF_WO3 589824
#define PF_WSR 655360
#define PF_WSK 720896

#define LDS_FLOATS 34944   // 139776 bytes

// Wave w owns output cols [16w,16w+16). Lane l: cols 16w + (l&1)*8 + [0,8),
// k-rows r*32 + (l>>1). Panel read = 64 consecutive u16x8 per round (1KB/wave).
__device__ __forceinline__ void gemv_acc(float acc[8], const u16* __restrict__ panel,
                                         const float* __restrict__ x, int w, int l) {
  const u16x8* __restrict__ p8 = reinterpret_cast<const u16x8*>(panel) + (w << 9) + l;
  const int xi = l >> 1;
#pragma unroll
  for (int r = 0; r < 8; ++r) {
    const u16x8 wv = p8[r << 6];
    const float xv = x[(r << 5) + xi];
#pragma unroll
    for (int j = 0; j < 8; ++j) {
      const float wf = __uint_as_float(((unsigned)wv[j]) << 16);
      acc[j] = fmaf(xv, wf, acc[j]);
    }
  }
}

__device__ __forceinline__ void xor_reduce8(float acc[8]) {
#pragma unroll
  for (int off = 2; off <= 32; off <<= 1) {
#pragma unroll
    for (int j = 0; j < 8; ++j) acc[j] += __shfl_xor(acc[j], off, 64);
  }
}

__global__ __launch_bounds__(1024, 4) void dagsage_main(
    const float* __restrict__ adj,
    const float* __restrict__ b_srep, const float* __restrict__ b_skey,
    const float* __restrict__ pf, const float* __restrict__ ph,
    const float* __restrict__ pq, const float* __restrict__ po,
    const u16* __restrict__ panels,
    float* __restrict__ out) {
  extern __shared__ float lds[];
  float* srep = lds;                 // [64][256]
  float* skey = srep + 16384;        // [64][256]
  float* hbuf = skey + 16384;        // [2][256] hidden ping-pong
  float* qbuf = hbuf + 512;          // [2][256] query ping-pong
  float* xqr  = qbuf + 512;          // [256] query_res
  float* xf   = xqr + 256;           // [256] forget
  float* xfh  = xf + 256;            // [256] forget*hidden
  float* xo   = xfh + 256;           // [256] out_i
  float* attw = xo + 256;            // [64]
  float* lrow = attw + 64;           // [64] logits

  const int t = threadIdx.x;
  const int w = t >> 6;              // wave 0..15
  const int l = t & 63;
  const int b = blockIdx.x;

  // out_nodes == 0 initially -> src rows are just the biases
  for (int idx = t; idx < 16384; idx += 1024) {
    const int c = idx & 255;
    srep[idx] = b_srep[c];
    skey[idx] = b_skey[c];
  }
  __syncthreads();

#pragma unroll 1
  for (int i = 0; i < 64; ++i) {
    const int bi = (b << 6) + i;
    const float* __restrict__ pf_row = pf + bi * 256;
    const float* __restrict__ ph_row = ph + bi * 256;
    const float* __restrict__ pq_row = pq + bi * 256;
    const float* __restrict__ po_row = po + bi * 256;

    if (t < 256) { hbuf[t] = 0.f; qbuf[t] = 0.f; }   // hidden=query=0 per step

    int p = 0;
#pragma unroll 1
    for (int it = 0; it < 3; ++it) {
      // ---- attention logits l[n] = query . src_keys[n] ----
      if (it > 0) {
        const int rr = l >> 4, ci = (l & 15) << 4;
        const int n = (w << 2) + rr;
        const float* q_ = qbuf + (p << 8);
        float s = 0.f;
#pragma unroll
        for (int j = 0; j < 16; ++j) s = fmaf(q_[ci + j], skey[(n << 8) + ci + j], s);
        s += __shfl_xor(s, 1, 64); s += __shfl_xor(s, 2, 64);
        s += __shfl_xor(s, 4, 64); s += __shfl_xor(s, 8, 64);
        if ((l & 15) == 0) lrow[n] = s;
        __syncthreads();
      }
      // ---- softmax (exp first, then mask, then normalize) : wave 0 ----
      if (w == 0) {
        float v = (it == 0) ? 0.f : lrow[l];
        float m = v;
#pragma unroll
        for (int off = 1; off < 64; off <<= 1) m = fmaxf(m, __shfl_xor(m, off, 64));
        const float e = __expf(v - m) * adj[((b << 6) + l) * 64 + i];
        float ssum = e;
#pragma unroll
        for (int off = 1; off < 64; off <<= 1) ssum += __shfl_xor(ssum, off, 64);
        attw[l] = e / ssum;
      }
      __syncthreads();
      // ---- query_res[c] = sum_n attw[n]*src_rep[n][c] ----
      {
        const int cc = l & 15, nn = l >> 4;
        const int c = (w << 4) + cc;
        float s = 0.f;
#pragma unroll
        for (int j = 0; j < 16; ++j) {
          const int n = nn + (j << 2);
          s = fmaf(attw[n], srep[(n << 8) + c], s);
        }
        s += __shfl_xor(s, 16, 64); s += __shfl_xor(s, 32, 64);
        if (l < 16) xqr[(w << 4) + l] = s;
      }
      __syncthreads();
      // ---- forget = sigmoid(Wf1.qres + Wf2.h + Wf4.q + pf) ----
      {
        float acc[8];
#pragma unroll
        for (int j = 0; j < 8; ++j) acc[j] = 0.f;
        gemv_acc(acc, panels + PF_WF1, xqr, w, l);
        if (it > 0) {
          gemv_acc(acc, panels + PF_WF2, hbuf + (p << 8), w, l);
          gemv_acc(acc, panels + PF_WF4, qbuf + (p << 8), w, l);
        }
        xor_reduce8(acc);
        if (l < 2) {
          const int c0 = (w << 4) + (l << 3);
#pragma unroll
          for (int j = 0; j < 8; ++j) {
            const float f = 1.f / (1.f + __expf(-(acc[j] + pf_row[c0 + j])));
            xf[c0 + j] = f;
            xfh[c0 + j] = f * hbuf[(p << 8) + c0 + j];
          }
        }
      }
      __syncthreads();
      // ---- hidden' = f*h + (1-f)*tanh(Wh1.qres + Wh2.(f*h) + Wh4.q + ph) ----
      {
        float acc[8];
#pragma unroll
        for (int j = 0; j < 8; ++j) acc[j] = 0.f;
        gemv_acc(acc, panels + PF_WH1, xqr, w, l);
        if (it > 0) {  // f*h == 0 and q == 0 exactly at it==0
          gemv_acc(acc, panels + PF_WH2, xfh, w, l);
          gemv_acc(acc, panels + PF_WH4, qbuf + (p << 8), w, l);
        }
        xor_reduce8(acc);
        if (l < 2) {
          const int c0 = (w << 4) + (l << 3);
#pragma unroll
          for (int j = 0; j < 8; ++j) {
            const float th = tanhf(acc[j] + ph_row[c0 + j]);
            const float f = xf[c0 + j];
            hbuf[((p ^ 1) << 8) + c0 + j] = xfh[c0 + j] + (1.f - f) * th;
          }
        }
      }
      __syncthreads();
      // ---- query' = Wq1.h' + Wq3.q + pq ----
      {
        float acc[8];
#pragma unroll
        for (int j = 0; j < 8; ++j) acc[j] = 0.f;
        gemv_acc(acc, panels + PF_WQ1, hbuf + ((p ^ 1) << 8), w, l);
        if (it > 0) gemv_acc(acc, panels + PF_WQ3, qbuf + (p << 8), w, l);
        xor_reduce8(acc);
        if (l < 2) {
          const int c0 = (w << 4) + (l << 3);
#pragma unroll
          for (int j = 0; j < 8; ++j)
            qbuf[((p ^ 1) << 8) + c0 + j] = acc[j] + pq_row[c0 + j];
        }
      }
      __syncthreads();
      p ^= 1;
    }
    // ---- out_i = Wo1.h + Wo3.q + po ----
    {
      float acc[8];
#pragma unroll
      for (int j = 0; j < 8; ++j) acc[j] = 0.f;
      gemv_acc(acc, panels + PF_WO1, hbuf + (p << 8), w, l);
      gemv_acc(acc, panels + PF_WO3, qbuf + (p << 8), w, l);
      xor_reduce8(acc);
      if (l < 2) {
        const int c0 = (w << 4) + (l << 3);
#pragma unroll
        for (int j = 0; j < 8; ++j) {
          const float v = acc[j] + po_row[c0 + j];
          xo[c0 + j] = v;
          out[bi * 256 + c0 + j] = v;
        }
      }
    }
    __syncthreads();
    // ---- incremental src updates: only row i changed ----
    {
      float acc[8];
#pragma unroll
      for (int j = 0; j < 8; ++j) acc[j] = 0.f;
      gemv_acc(acc, panels + PF_WSR, xo, w, l);
      xor_reduce8(acc);
      if (l < 2) {
        const int c0 = (w << 4) + (l << 3);
#pragma unroll
        for (int j = 0; j < 8; ++j) srep[(i << 8) + c0 + j] = acc[j] + b_srep[c0 + j];
      }
    }
    {
      float acc[8];
#pragma unroll
      for (int j = 0; j < 8; ++j) acc[j] = 0.f;
      gemv_acc(acc, panels + PF_WSK, xo, w, l);
      xor_reduce8(acc);
      if (l < 2) {
        const int c0 = (w << 4) + (l << 3);
#pragma unroll
        for (int j = 0; j < 8; ++j) skey[(i << 8) + c0 + j] = acc[j] + b_skey[c0 + j];
      }
    }
    __syncthreads();
  }
}

// ---------------------------------------------------------------------------
extern "C" void kernel_launch(void* const* d_in, const int* in_sizes, int n_in,
                              void* d_out, int out_size, void* d_ws, size_t ws_size,
                              hipStream_t stream) {
  const float* nodes    = (const float*)d_in[0];
  const float* adj      = (const float*)d_in[1];
  const float* W_self   = (const float*)d_in[2];
  const float* b_self   = (const float*)d_in[3];
  const float* W_srep   = (const float*)d_in[4];
  const float* b_srep   = (const float*)d_in[5];
  const float* W_skey   = (const float*)d_in[6];
  const float* b_skey   = (const float*)d_in[7];
  const float* W_forget = (const float*)d_in[8];
  const float* b_forget = (const float*)d_in[9];
  const float* W_hid    = (const float*)d_in[10];
  const float* b_hid    = (const float*)d_in[11];
  const float* W_query  = (const float*)d_in[12];
  const float* b_query  = (const float*)d_in[13];
  const float* W_out    = (const float*)d_in[14];
  const float* b_out    = (const float*)d_in[15];
  float* out = (float*)d_out;

  float* rep = (float*)d_ws;
  float* pf = rep + 524288;
  float* ph = pf + 524288;
  float* pq = ph + 524288;
  float* po = pq + 524288;
  u16* panels = (u16*)(po + 524288);

  // adj passes through to output slot 1
  hipMemcpyAsync(out + 524288, adj, 131072 * sizeof(float),
                 hipMemcpyDeviceToDevice, stream);

  // Convert/reblock the 12 weight panels to bf16
  C12 ca;
  ca.src[0] = W_forget;             // WF1 (rows 0:256   <- query_res)
  ca.src[1] = W_forget + 256 * 256; // WF2 (rows 256:512 <- hidden)
  ca.src[2] = W_forget + 768 * 256; // WF4 (rows 768:1024<- query)
  ca.src[3] = W_hid;                // WH1
  ca.src[4] = W_hid + 256 * 256;    // WH2 (<- f*h)
  ca.src[5] = W_hid + 768 * 256;    // WH4
  ca.src[6] = W_query;              // WQ1 (rows 0:256 <- hidden)
  ca.src[7] = W_query + 512 * 256;  // WQ3 (rows 512:768 <- query)
  ca.src[8] = W_out;                // WO1
  ca.src[9] = W_out + 512 * 256;    // WO3
  ca.src[10] = W_srep;              // WSR
  ca.src[11] = W_skey;              // WSK
  cvt_panels<<<dim3(256, 12), 256, 0, stream>>>(ca, panels);

  // rep = nodes @ W_self + b_self
  G4 g1;
  for (int j = 0; j < 4; ++j) { g1.Bm[j] = W_self; g1.bias[j] = b_self; g1.C[j] = rep; }
  gemm16<<<dim3(128, 1), 256, 0, stream>>>(nodes, g1);

  // pf/ph/pq/po = rep @ {Wf3, Wh3, Wq2, Wo2} + {b_forget, b_hid, b_query, b_out}
  G4 g2;
  g2.Bm[0] = W_forget + 512 * 256; g2.bias[0] = b_forget; g2.C[0] = pf;
  g2.Bm[1] = W_hid + 512 * 256;    g2.bias[1] = b_hid;    g2.C[1] = ph;
  g2.Bm[2] = W_query + 256 * 256;  g2.bias[2] = b_query;  g2.C[2] = pq;
  g2.Bm[3] = W_out + 256 * 256;    g2.bias[3] = b_out;    g2.C[3] = po;
  gemm16<<<dim3(128, 4), 256, 0, stream>>>(rep, g2);

  // main sequential recurrence: one workgroup per batch element
  const int lds_bytes = LDS_FLOATS * 4;
  hipFuncSetAttribute((const void*)dagsage_main,
                      hipFuncAttributeMaxDynamicSharedMemorySize, lds_bytes);
  dagsage_main<<<32, 1024, lds_bytes, stream>>>(adj, b_srep, b_skey, pf, ph, pq, po,
                                                panels, out);
}